// Round 3
// baseline (839.643 us; speedup 1.0000x reference)
//
#include <hip/hip_runtime.h>
#include <hip/hip_bf16.h>

#define B_ 8
#define H_ 128
#define W_ 256
#define PH 130          // H + 2 zero-pad rows
#define PW 258          // W + 2 zero-pad cols
#define NPIX (B_*64*H_*W_)

typedef short short8  __attribute__((ext_vector_type(8)));  // 8 bf16 (4 VGPRs)
typedef short short4v __attribute__((ext_vector_type(4)));  // 4 bf16 (8 B)
typedef float floatx4 __attribute__((ext_vector_type(4)));  // MFMA C/D

// ---------------------------------------------------------------------------
// Implicit-GEMM 3x3 SAME conv + bias + ReLU, bf16 MFMA 16x16x32, LDS-staged.
// Tile = 4 output rows x 64 px x all Co; 4 waves, wave r owns row r.
// R7: whole 4-conv chain runs in ONE persistent kernel (grid sized to exact
// co-residency via occupancy query); stages separated by a manual device-
// scope grid barrier. Per-stage tile loops are grid-stride, so a block's
// stage-i output tile is its stage-(i+1) input tile (same CU -> L2-warm),
// and stage-4 pairs (s,m0)->(s,m1) so the feat0 AVG read is L2-warm.
// ---------------------------------------------------------------------------
template<int Ci, int Co, bool LOSS, bool NCHW_IN>
struct conv_cfg {
    static constexpr int SCI  = NCHW_IN ? 32 : Ci;     // slab-resident channels
    static constexpr int PXB  = SCI*2;
    static constexpr int SLAB = 6*66*PXB;
    static constexpr int EPIW = 64*(Co+8)*2;
    static constexpr int RECB = 64*272*2;
    static constexpr int LDSZ = LOSS ? (RECB > SLAB ? RECB : SLAB)
                                     : (4*EPIW > SLAB ? 4*EPIW : SLAB);
};

template<int Ci, int Co, bool LOSS, bool NCHW_IN, bool AVG>
__device__ __forceinline__
void conv_tile(int tx, int ty, int bz, int mz,
               char* __restrict__ slab, float* __restrict__ wred,
               const void* __restrict__ inA,    // m0 input (bf16 NHWC / fp32 NCHW)
               const void* __restrict__ inB,    // m1 input
               const __hip_bfloat16* __restrict__ wt,   // [KC][Co][32] bf16
               const float* __restrict__ bias,
               __hip_bfloat16* __restrict__ outp,       // padded NHWC per-m
               size_t out_mstride,
               const float* __restrict__ ref0,          // fp32 NCHW (LOSS)
               const float* __restrict__ ref1,
               const float* __restrict__ other,         // feat0 (AVG, m1 only)
               float* __restrict__ avg_out,
               float* __restrict__ acc_out)
{
    constexpr int CC   = (Ci >= 32) ? Ci/32 : 1;
    constexpr int PXB  = conv_cfg<Ci,Co,LOSS,NCHW_IN>::PXB;
    constexpr int NCB  = PXB/16;
    constexpr int SLAB = conv_cfg<Ci,Co,LOSS,NCHW_IN>::SLAB;
    constexpr int NT   = Co/16;
    constexpr int GNT  = (NT >= 2) ? 2 : 1;
    constexpr int NG   = NT / GNT;
    constexpr int EPIW = conv_cfg<Ci,Co,LOSS,NCHW_IN>::EPIW;

    const int tid  = threadIdx.x;
    const int lane = tid & 63;
    const int wid  = tid >> 6;
    const int col  = lane & 15;
    const int quad = lane >> 4;
    const int w0   = tx * 64;
    const int h0   = ty * 4;
    const int r    = wid;

    __syncthreads();        // prior tile's slab reads complete before restage

    floatx4 acc[4][NT];
#pragma unroll
    for (int mt = 0; mt < 4; ++mt)
#pragma unroll
        for (int nt = 0; nt < NT; ++nt)
            acc[mt][nt] = (floatx4)0.f;

    // ---- per-c2 MFMA phase over the slab.
    auto mfma_c2 = [&](int c2) {
#pragma unroll
        for (int g = 0; g < NG; ++g) {
            short8 bfr[9*GNT];     // batched independent B loads
#pragma unroll
            for (int t = 0; t < 9; ++t)
#pragma unroll
                for (int j = 0; j < GNT; ++j)
                    bfr[t*GNT+j] = *(const short8*)(wt
                        + ((size_t)(c2*9+t)*Co + (g*GNT+j)*16 + col)*32 + quad*8);
#pragma unroll
            for (int t = 0; t < 9; ++t) {
                const int dy = t/3, dx = t - (t/3)*3;
                short8 a[4];
#pragma unroll
                for (int mt = 0; mt < 4; ++mt) {
                    int px  = (r+dy)*66 + mt*16 + col + dx;
                    int kch = NCHW_IN ? quad : (c2*4 + quad);
                    a[mt] = *(const short8*)(slab + px*PXB
                              + ((kch ^ (px & (NCB-1))) << 4));
                }
#pragma unroll
                for (int j = 0; j < GNT; ++j)
#pragma unroll
                    for (int mt = 0; mt < 4; ++mt)
                        acc[mt][g*GNT+j] = __builtin_amdgcn_mfma_f32_16x16x32_bf16(
                            a[mt], bfr[t*GNT+j], acc[mt][g*GNT+j], 0, 0, 0);
            }
        }
    };

    if constexpr (NCHW_IN) {
        // ---- fp32 NCHW feat, CC x {stage 32ch, compute} phases. Wave wid
        // owns 8-ch chunk; lanes = consecutive px (coalesced fp32 runs).
        static_assert(Ci == 64, "NCHW staging is Ci=64 only");
        const float* src = (const float*)(mz ? inB : inA) + (size_t)bz * 64 * H_ * W_;
#pragma unroll
        for (int c2 = 0; c2 < CC; ++c2) {
            if (c2) __syncthreads();             // prior-phase reads done
            const float* chb = src + (size_t)(c2*32 + wid*8) * (H_*W_);
#pragma unroll
            for (int it = 0; it < 7; ++it) {
                int pxl = it*64 + lane;          // 0..395 live (6 rows x 66)
                bool live = (it < 6) || (lane < 12);
                int row = pxl / 66;
                int pxc = pxl - row*66;
                int gh  = h0 + row - 1;
                int gw  = w0 + pxc - 1;
                bool ok = live && ((unsigned)gh < (unsigned)H_)
                               && ((unsigned)gw < (unsigned)W_);
                const float* sp = chb + (size_t)(ok ? gh : 0)*W_ + (ok ? gw : 0);
                short8 v;
#pragma unroll
                for (int j = 0; j < 8; ++j) {
                    float f = sp[(size_t)j*(H_*W_)];
                    v[j] = __builtin_bit_cast(short, __float2bfloat16(ok ? f : 0.f));
                }
                if (live)
                    *(short8*)(slab + pxl*PXB + ((wid ^ (pxl & (NCB-1))) << 4)) = v;
            }
            __syncthreads();
            mfma_c2(c2);
        }
    } else {
        // ---- stage slab from padded bf16 NHWC: coalesced 16B chunks.
        const __hip_bfloat16* inb = (const __hip_bfloat16*)(mz ? inB : inA)
                                    + (size_t)bz * PH * PW * Ci;
        for (int o = tid*16; o < SLAB; o += 4096) {
            int pxl = o / PXB;
            int row = pxl / 66;
            int pxc = pxl - row*66;
            int cb  = (o >> 4) & (NCB-1);
            short8 v = *(const short8*)(inb + ((size_t)(h0+row)*PW + (w0+pxc))*Ci + cb*8);
            *(short8*)(slab + pxl*PXB + ((cb ^ (pxl & (NCB-1))) << 4)) = v;
        }
        __syncthreads();

        if constexpr (Ci >= 32) {
#pragma unroll
            for (int c2 = 0; c2 < CC; ++c2)
                mfma_c2(c2);
        } else {
            // Ci=16: K=32 packs 2 dx taps; half1 upper quads carry zero weights.
            short8 bfr[6*NT];
#pragma unroll
            for (int kc = 0; kc < 6; ++kc)
#pragma unroll
                for (int j = 0; j < NT; ++j)
                    bfr[kc*NT+j] = *(const short8*)(wt
                        + ((size_t)kc*Co + j*16 + col)*32 + quad*8);
#pragma unroll
            for (int kc = 0; kc < 6; ++kc) {
                const int dy = kc >> 1, half = kc & 1;
                const int dxe = half ? 2 : (quad >> 1);
                short8 a[4];
#pragma unroll
                for (int mt = 0; mt < 4; ++mt) {
                    int px = (r+dy)*66 + mt*16 + col + dxe;
                    a[mt] = *(const short8*)(slab + px*PXB
                              + (((quad & 1) ^ (px & 1)) << 4));
                }
#pragma unroll
                for (int j = 0; j < NT; ++j)
#pragma unroll
                    for (int mt = 0; mt < 4; ++mt)
                        acc[mt][j] = __builtin_amdgcn_mfma_f32_16x16x32_bf16(
                            a[mt], bfr[kc*NT+j], acc[mt][j], 0, 0, 0);
            }
        }
    }

    if constexpr (!LOSS) {
        __syncthreads();
        char* rt = slab + wid * EPIW;     // per-wave [64 px][Co+8] bf16 tile
#pragma unroll
        for (int nt = 0; nt < NT; ++nt) {
            float bv = bias[nt*16 + col];
#pragma unroll
            for (int mt = 0; mt < 4; ++mt) {
#pragma unroll
                for (int rr = 0; rr < 4; ++rr) {
                    float v = acc[mt][nt][rr] + bv;
                    v = v > 0.f ? v : 0.f;
                    int px = mt*16 + quad*4 + rr;
                    *(__hip_bfloat16*)(rt + (px*(Co+8) + nt*16 + col)*2) =
                        __float2bfloat16(v);
                }
            }
        }
        __hip_bfloat16* ob = outp + (size_t)mz * out_mstride;
        char* grow = (char*)ob
            + (((size_t)bz*PH + (h0 + r + 1))*PW + (w0 + 1))*Co*2;
        constexpr int GB = 64*Co*2;
#pragma unroll
        for (int id = 0; id < GB/1024; ++id) {
            int o  = id*1024 + lane*16;
            int px = o / (Co*2);
            int cb = o - px*(Co*2);
            *(short8*)(grow + o) = *(const short8*)(rt + px*(Co+8)*2 + cb);
        }
    } else {
        // ---- rec -> LDS bf16 [co][row][68] (b64-aligned), barriered
        __syncthreads();                        // all slab reads complete
        __hip_bfloat16* rec = (__hip_bfloat16*)slab;
#pragma unroll
        for (int nt = 0; nt < NT; ++nt) {
            int co = nt*16 + col;
            float bv = bias[co];
#pragma unroll
            for (int mt = 0; mt < 4; ++mt) {
                short4v pk;
#pragma unroll
                for (int rr = 0; rr < 4; ++rr) {
                    float v = acc[mt][nt][rr] + bv;
                    v = v > 0.f ? v : 0.f;
                    pk[rr] = __builtin_bit_cast(short, __float2bfloat16(v));
                }
                *(short4v*)(rec + co*272 + r*68 + mt*16 + quad*4) = pk;
            }
        }
        __syncthreads();

        // ---- coalesced fp32 ref compare: 16 iters, 256B contiguous per co.
        // AVG (m1 only): same tile addresses -> fused = 0.5*(f0+f1).
        float lsum = 0.f;
        const float* refb = (mz ? ref1 : ref0) + (size_t)bz * 64 * H_ * W_;
#pragma unroll
        for (int i = 0; i < 16; ++i) {
            int row = i & 3, cg = i >> 2;
            int co  = cg*16 + wid*4 + quad;
            size_t off = ((size_t)co*H_ + h0 + row)*W_ + w0 + col*4;
            float4 f = *(const float4*)(refb + off);
            short4v pk = *(const short4v*)(rec + co*272 + row*68 + col*4);
            float d0 = f.x - __bfloat162float(__builtin_bit_cast(__hip_bfloat16, pk[0]));
            float d1 = f.y - __bfloat162float(__builtin_bit_cast(__hip_bfloat16, pk[1]));
            float d2 = f.z - __bfloat162float(__builtin_bit_cast(__hip_bfloat16, pk[2]));
            float d3 = f.w - __bfloat162float(__builtin_bit_cast(__hip_bfloat16, pk[3]));
            lsum += d0*d0 + d1*d1 + d2*d2 + d3*d3;
            if constexpr (AVG) {
                if (mz) {
                    const float* othb = other + (size_t)bz * 64 * H_ * W_;
                    float*       avgb = avg_out + (size_t)bz * 64 * H_ * W_;
                    float4 g = *(const float4*)(othb + off);
                    float4 o;
                    o.x = 0.5f*(f.x + g.x);
                    o.y = 0.5f*(f.y + g.y);
                    o.z = 0.5f*(f.z + g.z);
                    o.w = 0.5f*(f.w + g.w);
                    *(float4*)(avgb + off) = o;
                }
            }
        }
#pragma unroll
        for (int off = 32; off > 0; off >>= 1)
            lsum += __shfl_down(lsum, off, 64);
        if (lane == 0) wred[wid] = lsum;
        __syncthreads();
        if (tid == 0)      // 1/NPIX = 2^-24 exact: finalize folded into atomic
            atomicAdd(acc_out, (wred[0] + wred[1] + wred[2] + wred[3])
                               * (1.0f / (float)NPIX));
    }
}

// ---------------------------------------------------------------------------
// Manual device-scope grid barrier. Safe because grid <= exact co-resident
// capacity (occupancy-query-sized). Monotonic counter; target = k*gridDim.
// ---------------------------------------------------------------------------
__device__ __forceinline__ void grid_sync(int* cnt, int target)
{
    __syncthreads();
    if (threadIdx.x == 0) {
        __threadfence();                                  // release stage-i writes
        __hip_atomic_fetch_add(cnt, 1, __ATOMIC_ACQ_REL, __HIP_MEMORY_SCOPE_AGENT);
        while (__hip_atomic_load(cnt, __ATOMIC_ACQUIRE, __HIP_MEMORY_SCOPE_AGENT)
               < target)
            __builtin_amdgcn_s_sleep(1);
        __threadfence();                                  // acquire for this CU
    }
    __syncthreads();
}

// ---------------------------------------------------------------------------
// Persistent fused chain: conv1..conv4 with grid barriers between stages.
// LDS = max over stages (RECB = 34816). 4 blocks/CU via launch_bounds(256,4).
// ---------------------------------------------------------------------------
__global__ __launch_bounds__(256, 4)
void fused_chain(const float* __restrict__ feat0, const float* __restrict__ feat1,
                 const __hip_bfloat16* __restrict__ WT1,
                 const __hip_bfloat16* __restrict__ WT2,
                 const __hip_bfloat16* __restrict__ WT3,
                 const __hip_bfloat16* __restrict__ WT4,
                 const float* __restrict__ b1, const float* __restrict__ b2,
                 const float* __restrict__ b3, const float* __restrict__ b4,
                 __hip_bfloat16* __restrict__ BUF1, __hip_bfloat16* __restrict__ BUF2,
                 float* __restrict__ avg_out, float* __restrict__ acc,
                 int* __restrict__ cnt)
{
    constexpr int LDSZ = 64*272*2;                 // 34816: max over stages
    __shared__ alignas(16) char slab[LDSZ + 32];
    __shared__ float wred[4];
    constexpr size_t B1E = (size_t)B_*PH*PW*32;    // bf16-elem modality stride
    constexpr size_t B2E = (size_t)B_*PH*PW*16;
    const int gsz = gridDim.x;

    int tx, ty, bz, mz;
    auto dec = [&](int t) {
        tx = t & 3; ty = (t >> 2) & 31; bz = (t >> 7) & 7; mz = t >> 10;
    };

    for (int t = blockIdx.x; t < 2048; t += gsz) {
        dec(t);
        conv_tile<64,32,false,true ,false>(tx,ty,bz,mz, slab, wred,
            feat0, feat1, WT1, b1, BUF1, B1E,
            nullptr, nullptr, nullptr, nullptr, nullptr);
    }
    grid_sync(cnt, 1*gsz);
    for (int t = blockIdx.x; t < 2048; t += gsz) {
        dec(t);
        conv_tile<32,16,false,false,false>(tx,ty,bz,mz, slab, wred,
            BUF1, BUF1 + B1E, WT2, b2, BUF2, B2E,
            nullptr, nullptr, nullptr, nullptr, nullptr);
    }
    grid_sync(cnt, 2*gsz);
    for (int t = blockIdx.x; t < 2048; t += gsz) {
        dec(t);
        conv_tile<16,32,false,false,false>(tx,ty,bz,mz, slab, wred,
            BUF2, BUF2 + B2E, WT3, b3, BUF1, B1E,
            nullptr, nullptr, nullptr, nullptr, nullptr);
    }
    grid_sync(cnt, 3*gsz);
    for (int t = blockIdx.x; t < 2048; t += gsz) {
        dec(t);        // (s,m0) then (s,m1): feat0 tile L2-warm for AVG
        conv_tile<32,64,true ,false,true >(tx,ty,bz,mz, slab, wred,
            BUF1, BUF1 + B1E, WT4, b4, nullptr, 0,
            feat0, feat1, feat0, avg_out, acc);
    }
}

// ---------------------------------------------------------------------------
// Standalone per-stage kernels (fallback path only).
// ---------------------------------------------------------------------------
template<int Ci, int Co, bool LOSS, bool NCHW_IN, bool AVG>
__global__ __launch_bounds__(256)
void conv_mfma(const void* __restrict__ inA, const void* __restrict__ inB,
               const __hip_bfloat16* __restrict__ wt, const float* __restrict__ bias,
               __hip_bfloat16* __restrict__ outp, size_t out_mstride,
               const float* __restrict__ ref0, const float* __restrict__ ref1,
               const float* __restrict__ other, float* __restrict__ avg_out,
               float* __restrict__ acc_out)
{
    constexpr int LDSZ = conv_cfg<Ci,Co,LOSS,NCHW_IN>::LDSZ;
    __shared__ alignas(16) char slab[LDSZ + 32];
    __shared__ float wred[4];
    conv_tile<Ci,Co,LOSS,NCHW_IN,AVG>(blockIdx.x, blockIdx.y,
        blockIdx.z & 7, blockIdx.z >> 3, slab, wred,
        inA, inB, wt, bias, outp, out_mstride, ref0, ref1, other, avg_out, acc_out);
}

// ---------------------------------------------------------------------------
// Border-zero work item: pad cells of a padded NHWC buffer (772 px / image).
// ---------------------------------------------------------------------------
template<int C>
__device__ __forceinline__ void zb_item(__hip_bfloat16* buf, int idx)
{
    constexpr int CP = C/8;
    int cb   = idx % CP;
    int cell = (idx / CP) % 772;
    int img  = idx / (CP*772);
    int row, colp;
    if (cell < 258)      { row = 0;   colp = cell; }
    else if (cell < 516) { row = 129; colp = cell - 258; }
    else { int r2 = cell - 516; row = 1 + (r2 >> 1); colp = (r2 & 1) ? 257 : 0; }
    short8 z = (short8)0;
    *(short8*)(buf + (((size_t)img*PH + row)*PW + colp)*C + cb*8) = z;
}

// ---------------------------------------------------------------------------
// OIHW fp32 -> [KC][Co][32] bf16 B-operand work item.
// ---------------------------------------------------------------------------
template<int Ci, int Co>
__device__ __forceinline__ void wt_item(const float* __restrict__ w,
                                        __hip_bfloat16* __restrict__ wt, int idx)
{
    int kl = idx & 31;
    int co = (idx >> 5) % Co;
    int kc = idx / (32*Co);
    float val = 0.f;
    if constexpr (Ci >= 32) {
        int c2 = kc / 9, t = kc % 9;
        int dy = t/3, dx = t%3;
        int ci = c2*32 + kl;
        val = w[((size_t)(co*Ci + ci)*3 + dy)*3 + dx];
    } else {
        int dy = kc >> 1, half = kc & 1;
        int dx = half*2 + (kl >> 4);
        int ci = kl & 15;
        if (dx < 3) val = w[((size_t)(co*Ci + ci)*3 + dy)*3 + dx];
    }
    wt[idx] = __float2bfloat16(val);
}

// ---------------------------------------------------------------------------
// One setup dispatch: border zeros (both modalities) + 4 wt transforms +
// acc=0 + barrier counter = 0. Total 121728 items.
// ---------------------------------------------------------------------------
__global__ __launch_bounds__(256)
void setup_kernel(const float* __restrict__ w1, const float* __restrict__ w2,
                  const float* __restrict__ w3, const float* __restrict__ w4,
                  __hip_bfloat16* WT1, __hip_bfloat16* WT2,
                  __hip_bfloat16* WT3, __hip_bfloat16* WT4,
                  __hip_bfloat16* BUF1, __hip_bfloat16* BUF2,
                  float* acc, int* cnt)
{
    int idx = blockIdx.x*256 + threadIdx.x;
    if (idx == 0) { *acc = 0.f; *cnt = 0; }
    if      (idx <  49408) zb_item<32>(BUF1, idx);
    else if (idx <  74112) zb_item<16>(BUF2, idx - 49408);
    else if (idx <  92544) wt_item<64,32>(w1, WT1, idx - 74112);
    else if (idx <  97152) wt_item<32,16>(w2, WT2, idx - 92544);
    else if (idx < 103296) wt_item<16,32>(w3, WT3, idx - 97152);
    else if (idx < 121728) wt_item<32,64>(w4, WT4, idx - 103296);
}

// fused_feat = 0.5*(feat0+feat1) exactly. Fallback path only.
__global__ __launch_bounds__(256)
void fused_avg_kernel(const float4* __restrict__ a, const float4* __restrict__ b,
                      float4* __restrict__ o, int n4)
{
    int i = blockIdx.x*256 + threadIdx.x;
    if (i < n4) {
        float4 x = a[i], y = b[i];
        float4 r;
        r.x = 0.5f*(x.x + y.x);
        r.y = 0.5f*(x.y + y.y);
        r.z = 0.5f*(x.z + y.z);
        r.w = 0.5f*(x.w + y.w);
        o[i] = r;
    }
}

extern "C" void kernel_launch(void* const* d_in, const int* in_sizes, int n_in,
                              void* d_out, int out_size, void* d_ws, size_t ws_size,
                              hipStream_t stream)
{
    const float* feat0 = (const float*)d_in[0];
    const float* feat1 = (const float*)d_in[1];
    const float* w1 = (const float*)d_in[2];
    const float* b1 = (const float*)d_in[3];
    const float* w2 = (const float*)d_in[4];
    const float* b2 = (const float*)d_in[5];
    const float* w3 = (const float*)d_in[6];
    const float* b3 = (const float*)d_in[7];
    const float* w4 = (const float*)d_in[8];
    const float* b4 = (const float*)d_in[9];

    float* out = (float*)d_out;
    float* acc = out + NPIX;                 // loss output slot

    // Scratch layout (total 51,612,736 B):
    //   BUF1[2] @ 0 (2 x 17,172,480) | BUF2[2] @ 34344960 (2 x 8,586,240)
    //   WT1 @ 51517440 | WT2 @ 51554304 | WT3 @ 51563520 | WT4 @ 51575808
    //   barrier counter @ 51612672
    constexpr size_t B1B = (size_t)B_*PH*PW*32*2;
    constexpr size_t SCR_SZ = 51612736;
    const bool use_ws = (d_ws != nullptr) && (ws_size >= SCR_SZ);
    char* sb = use_ws ? (char*)d_ws : (char*)d_out;  // fallback: out written last

    __hip_bfloat16* BUF1 = (__hip_bfloat16*)(sb + 0);
    __hip_bfloat16* BUF2 = (__hip_bfloat16*)(sb + 2*B1B);
    __hip_bfloat16* WT1  = (__hip_bfloat16*)(sb + 51517440);
    __hip_bfloat16* WT2  = (__hip_bfloat16*)(sb + 51554304);
    __hip_bfloat16* WT3  = (__hip_bfloat16*)(sb + 51563520);
    __hip_bfloat16* WT4  = (__hip_bfloat16*)(sb + 51575808);
    int*            CNT  = (int*)(sb + 51612672);

    setup_kernel<<<476, 256, 0, stream>>>(w1, w2, w3, w4,
                                          WT1, WT2, WT3, WT4, BUF1, BUF2, acc, CNT);

    // Exact co-resident grid for the persistent kernel (cached).
    static int g_nblk = 0;
    if (g_nblk == 0) {
        int bpc = 0;
        if (hipOccupancyMaxActiveBlocksPerMultiprocessor(&bpc, fused_chain, 256, 0)
                != hipSuccess || bpc < 1)
            bpc = 0;
        int dev = 0; hipGetDevice(&dev);
        int ncu = 0;
        if (hipDeviceGetAttribute(&ncu, hipDeviceAttributeMultiprocessorCount, dev)
                != hipSuccess || ncu <= 0)
            ncu = 256;
        g_nblk = (bpc >= 1) ? bpc * ncu : -1;
        if (g_nblk > 2048) g_nblk = 2048;
    }

    constexpr size_t B1E = B1B/2;
    constexpr size_t B2E = (size_t)B_*PH*PW*16;

    if (use_ws && g_nblk > 0) {
        fused_chain<<<g_nblk, 256, 0, stream>>>(
            feat0, feat1, WT1, WT2, WT3, WT4, b1, b2, b3, b4,
            BUF1, BUF2, out, acc, CNT);
    } else {
        dim3 cgrid(W_/64, H_/4, 2*B_);
        dim3 blk(256);
        conv_mfma<64,32,false,true ,false><<<cgrid, blk, 0, stream>>>(
            feat0, feat1, WT1, b1, BUF1, B1E,
            nullptr, nullptr, nullptr, nullptr, nullptr);
        conv_mfma<32,16,false,false,false><<<cgrid, blk, 0, stream>>>(
            BUF1, BUF1 + B1E, WT2, b2, BUF2, B2E,
            nullptr, nullptr, nullptr, nullptr, nullptr);
        conv_mfma<16,32,false,false,false><<<cgrid, blk, 0, stream>>>(
            BUF2, BUF2 + B2E, WT3, b3, BUF1, B1E,
            nullptr, nullptr, nullptr, nullptr, nullptr);
        if (use_ws)
            conv_mfma<32,64,true ,false,true ><<<cgrid, blk, 0, stream>>>(
                BUF1, BUF1 + B1E, WT4, b4, nullptr, 0,
                feat0, feat1, feat0, out, acc);
        else {
            conv_mfma<32,64,true ,false,false><<<cgrid, blk, 0, stream>>>(
                BUF1, BUF1 + B1E, WT4, b4, nullptr, 0,
                feat0, feat1, nullptr, nullptr, acc);
            int n4 = NPIX/4;
            fused_avg_kernel<<<(n4 + 255)/256, 256, 0, stream>>>(
                (const float4*)feat0, (const float4*)feat1, (float4*)out, n4);
        }
    }
}

// Round 4
// 318.494 us; speedup vs baseline: 2.6363x; 2.6363x over previous
//
#include <hip/hip_runtime.h>
#include <hip/hip_bf16.h>

#define B_ 8
#define H_ 128
#define W_ 256
#define PH 130          // H + 2 zero-pad rows
#define PW 258          // W + 2 zero-pad cols
#define NPIX (B_*64*H_*W_)

typedef short short8  __attribute__((ext_vector_type(8)));  // 8 bf16 (4 VGPRs)
typedef short short4v __attribute__((ext_vector_type(4)));  // 4 bf16 (8 B)
typedef float floatx4 __attribute__((ext_vector_type(4)));  // MFMA C/D

// ---------------------------------------------------------------------------
// Implicit-GEMM 3x3 SAME conv + bias + ReLU, bf16 MFMA 16x16x32, LDS-staged.
// Tile = 4 output rows x 64 px x all Co; 4 waves, wave r owns row r.
// R8 = R7 with ONE change: fused_chain uses __launch_bounds__(256) (no
// min-waves clamp). R7's (256,4) forced VGPR=64 -> massive scratch spills
// (FETCH +240MB, MfmaUtil 9%->1.9%). Natural regalloc (~100-128 VGPR) keeps
// the conv bodies spill-free; occupancy query sizes the persistent grid.
// ---------------------------------------------------------------------------
template<int Ci, int Co, bool LOSS, bool NCHW_IN>
struct conv_cfg {
    static constexpr int SCI  = NCHW_IN ? 32 : Ci;     // slab-resident channels
    static constexpr int PXB  = SCI*2;
    static constexpr int SLAB = 6*66*PXB;
    static constexpr int EPIW = 64*(Co+8)*2;
    static constexpr int RECB = 64*272*2;
    static constexpr int LDSZ = LOSS ? (RECB > SLAB ? RECB : SLAB)
                                     : (4*EPIW > SLAB ? 4*EPIW : SLAB);
};

template<int Ci, int Co, bool LOSS, bool NCHW_IN, bool AVG>
__device__ __forceinline__
void conv_tile(int tx, int ty, int bz, int mz,
               char* __restrict__ slab, float* __restrict__ wred,
               const void* __restrict__ inA,    // m0 input (bf16 NHWC / fp32 NCHW)
               const void* __restrict__ inB,    // m1 input
               const __hip_bfloat16* __restrict__ wt,   // [KC][Co][32] bf16
               const float* __restrict__ bias,
               __hip_bfloat16* __restrict__ outp,       // padded NHWC per-m
               size_t out_mstride,
               const float* __restrict__ ref0,          // fp32 NCHW (LOSS)
               const float* __restrict__ ref1,
               const float* __restrict__ other,         // feat0 (AVG, m1 only)
               float* __restrict__ avg_out,
               float* __restrict__ acc_out)
{
    constexpr int CC   = (Ci >= 32) ? Ci/32 : 1;
    constexpr int PXB  = conv_cfg<Ci,Co,LOSS,NCHW_IN>::PXB;
    constexpr int NCB  = PXB/16;
    constexpr int SLAB = conv_cfg<Ci,Co,LOSS,NCHW_IN>::SLAB;
    constexpr int NT   = Co/16;
    constexpr int GNT  = (NT >= 2) ? 2 : 1;
    constexpr int NG   = NT / GNT;
    constexpr int EPIW = conv_cfg<Ci,Co,LOSS,NCHW_IN>::EPIW;

    const int tid  = threadIdx.x;
    const int lane = tid & 63;
    const int wid  = tid >> 6;
    const int col  = lane & 15;
    const int quad = lane >> 4;
    const int w0   = tx * 64;
    const int h0   = ty * 4;
    const int r    = wid;

    __syncthreads();        // prior tile's slab reads complete before restage

    floatx4 acc[4][NT];
#pragma unroll
    for (int mt = 0; mt < 4; ++mt)
#pragma unroll
        for (int nt = 0; nt < NT; ++nt)
            acc[mt][nt] = (floatx4)0.f;

    // ---- per-c2 MFMA phase over the slab.
    auto mfma_c2 = [&](int c2) {
#pragma unroll
        for (int g = 0; g < NG; ++g) {
            short8 bfr[9*GNT];     // batched independent B loads
#pragma unroll
            for (int t = 0; t < 9; ++t)
#pragma unroll
                for (int j = 0; j < GNT; ++j)
                    bfr[t*GNT+j] = *(const short8*)(wt
                        + ((size_t)(c2*9+t)*Co + (g*GNT+j)*16 + col)*32 + quad*8);
#pragma unroll
            for (int t = 0; t < 9; ++t) {
                const int dy = t/3, dx = t - (t/3)*3;
                short8 a[4];
#pragma unroll
                for (int mt = 0; mt < 4; ++mt) {
                    int px  = (r+dy)*66 + mt*16 + col + dx;
                    int kch = NCHW_IN ? quad : (c2*4 + quad);
                    a[mt] = *(const short8*)(slab + px*PXB
                              + ((kch ^ (px & (NCB-1))) << 4));
                }
#pragma unroll
                for (int j = 0; j < GNT; ++j)
#pragma unroll
                    for (int mt = 0; mt < 4; ++mt)
                        acc[mt][g*GNT+j] = __builtin_amdgcn_mfma_f32_16x16x32_bf16(
                            a[mt], bfr[t*GNT+j], acc[mt][g*GNT+j], 0, 0, 0);
            }
        }
    };

    if constexpr (NCHW_IN) {
        // ---- fp32 NCHW feat, CC x {stage 32ch, compute} phases. Wave wid
        // owns 8-ch chunk; lanes = consecutive px (coalesced fp32 runs).
        static_assert(Ci == 64, "NCHW staging is Ci=64 only");
        const float* src = (const float*)(mz ? inB : inA) + (size_t)bz * 64 * H_ * W_;
#pragma unroll
        for (int c2 = 0; c2 < CC; ++c2) {
            if (c2) __syncthreads();             // prior-phase reads done
            const float* chb = src + (size_t)(c2*32 + wid*8) * (H_*W_);
#pragma unroll
            for (int it = 0; it < 7; ++it) {
                int pxl = it*64 + lane;          // 0..395 live (6 rows x 66)
                bool live = (it < 6) || (lane < 12);
                int row = pxl / 66;
                int pxc = pxl - row*66;
                int gh  = h0 + row - 1;
                int gw  = w0 + pxc - 1;
                bool ok = live && ((unsigned)gh < (unsigned)H_)
                               && ((unsigned)gw < (unsigned)W_);
                const float* sp = chb + (size_t)(ok ? gh : 0)*W_ + (ok ? gw : 0);
                short8 v;
#pragma unroll
                for (int j = 0; j < 8; ++j) {
                    float f = sp[(size_t)j*(H_*W_)];
                    v[j] = __builtin_bit_cast(short, __float2bfloat16(ok ? f : 0.f));
                }
                if (live)
                    *(short8*)(slab + pxl*PXB + ((wid ^ (pxl & (NCB-1))) << 4)) = v;
            }
            __syncthreads();
            mfma_c2(c2);
        }
    } else {
        // ---- stage slab from padded bf16 NHWC: coalesced 16B chunks.
        const __hip_bfloat16* inb = (const __hip_bfloat16*)(mz ? inB : inA)
                                    + (size_t)bz * PH * PW * Ci;
        for (int o = tid*16; o < SLAB; o += 4096) {
            int pxl = o / PXB;
            int row = pxl / 66;
            int pxc = pxl - row*66;
            int cb  = (o >> 4) & (NCB-1);
            short8 v = *(const short8*)(inb + ((size_t)(h0+row)*PW + (w0+pxc))*Ci + cb*8);
            *(short8*)(slab + pxl*PXB + ((cb ^ (pxl & (NCB-1))) << 4)) = v;
        }
        __syncthreads();

        if constexpr (Ci >= 32) {
#pragma unroll
            for (int c2 = 0; c2 < CC; ++c2)
                mfma_c2(c2);
        } else {
            // Ci=16: K=32 packs 2 dx taps; half1 upper quads carry zero weights.
            short8 bfr[6*NT];
#pragma unroll
            for (int kc = 0; kc < 6; ++kc)
#pragma unroll
                for (int j = 0; j < NT; ++j)
                    bfr[kc*NT+j] = *(const short8*)(wt
                        + ((size_t)kc*Co + j*16 + col)*32 + quad*8);
#pragma unroll
            for (int kc = 0; kc < 6; ++kc) {
                const int dy = kc >> 1, half = kc & 1;
                const int dxe = half ? 2 : (quad >> 1);
                short8 a[4];
#pragma unroll
                for (int mt = 0; mt < 4; ++mt) {
                    int px = (r+dy)*66 + mt*16 + col + dxe;
                    a[mt] = *(const short8*)(slab + px*PXB
                              + (((quad & 1) ^ (px & 1)) << 4));
                }
#pragma unroll
                for (int j = 0; j < NT; ++j)
#pragma unroll
                    for (int mt = 0; mt < 4; ++mt)
                        acc[mt][j] = __builtin_amdgcn_mfma_f32_16x16x32_bf16(
                            a[mt], bfr[kc*NT+j], acc[mt][j], 0, 0, 0);
            }
        }
    }

    if constexpr (!LOSS) {
        __syncthreads();
        char* rt = slab + wid * EPIW;     // per-wave [64 px][Co+8] bf16 tile
#pragma unroll
        for (int nt = 0; nt < NT; ++nt) {
            float bv = bias[nt*16 + col];
#pragma unroll
            for (int mt = 0; mt < 4; ++mt) {
#pragma unroll
                for (int rr = 0; rr < 4; ++rr) {
                    float v = acc[mt][nt][rr] + bv;
                    v = v > 0.f ? v : 0.f;
                    int px = mt*16 + quad*4 + rr;
                    *(__hip_bfloat16*)(rt + (px*(Co+8) + nt*16 + col)*2) =
                        __float2bfloat16(v);
                }
            }
        }
        __hip_bfloat16* ob = outp + (size_t)mz * out_mstride;
        char* grow = (char*)ob
            + (((size_t)bz*PH + (h0 + r + 1))*PW + (w0 + 1))*Co*2;
        constexpr int GB = 64*Co*2;
#pragma unroll
        for (int id = 0; id < GB/1024; ++id) {
            int o  = id*1024 + lane*16;
            int px = o / (Co*2);
            int cb = o - px*(Co*2);
            *(short8*)(grow + o) = *(const short8*)(rt + px*(Co+8)*2 + cb);
        }
    } else {
        // ---- rec -> LDS bf16 [co][row][68] (b64-aligned), barriered
        __syncthreads();                        // all slab reads complete
        __hip_bfloat16* rec = (__hip_bfloat16*)slab;
#pragma unroll
        for (int nt = 0; nt < NT; ++nt) {
            int co = nt*16 + col;
            float bv = bias[co];
#pragma unroll
            for (int mt = 0; mt < 4; ++mt) {
                short4v pk;
#pragma unroll
                for (int rr = 0; rr < 4; ++rr) {
                    float v = acc[mt][nt][rr] + bv;
                    v = v > 0.f ? v : 0.f;
                    pk[rr] = __builtin_bit_cast(short, __float2bfloat16(v));
                }
                *(short4v*)(rec + co*272 + r*68 + mt*16 + quad*4) = pk;
            }
        }
        __syncthreads();

        // ---- coalesced fp32 ref compare: 16 iters, 256B contiguous per co.
        // AVG (m1 only): same tile addresses -> fused = 0.5*(f0+f1).
        float lsum = 0.f;
        const float* refb = (mz ? ref1 : ref0) + (size_t)bz * 64 * H_ * W_;
#pragma unroll
        for (int i = 0; i < 16; ++i) {
            int row = i & 3, cg = i >> 2;
            int co  = cg*16 + wid*4 + quad;
            size_t off = ((size_t)co*H_ + h0 + row)*W_ + w0 + col*4;
            float4 f = *(const float4*)(refb + off);
            short4v pk = *(const short4v*)(rec + co*272 + row*68 + col*4);
            float d0 = f.x - __bfloat162float(__builtin_bit_cast(__hip_bfloat16, pk[0]));
            float d1 = f.y - __bfloat162float(__builtin_bit_cast(__hip_bfloat16, pk[1]));
            float d2 = f.z - __bfloat162float(__builtin_bit_cast(__hip_bfloat16, pk[2]));
            float d3 = f.w - __bfloat162float(__builtin_bit_cast(__hip_bfloat16, pk[3]));
            lsum += d0*d0 + d1*d1 + d2*d2 + d3*d3;
            if constexpr (AVG) {
                if (mz) {
                    const float* othb = other + (size_t)bz * 64 * H_ * W_;
                    float*       avgb = avg_out + (size_t)bz * 64 * H_ * W_;
                    float4 g = *(const float4*)(othb + off);
                    float4 o;
                    o.x = 0.5f*(f.x + g.x);
                    o.y = 0.5f*(f.y + g.y);
                    o.z = 0.5f*(f.z + g.z);
                    o.w = 0.5f*(f.w + g.w);
                    *(float4*)(avgb + off) = o;
                }
            }
        }
#pragma unroll
        for (int off = 32; off > 0; off >>= 1)
            lsum += __shfl_down(lsum, off, 64);
        if (lane == 0) wred[wid] = lsum;
        __syncthreads();
        if (tid == 0)      // 1/NPIX = 2^-24 exact: finalize folded into atomic
            atomicAdd(acc_out, (wred[0] + wred[1] + wred[2] + wred[3])
                               * (1.0f / (float)NPIX));
    }
}

// ---------------------------------------------------------------------------
// Manual device-scope grid barrier. Safe because grid <= exact co-resident
// capacity (occupancy-query-sized). Monotonic counter; target = k*gridDim.
// ---------------------------------------------------------------------------
__device__ __forceinline__ void grid_sync(int* cnt, int target)
{
    __syncthreads();
    if (threadIdx.x == 0) {
        __threadfence();                                  // release stage-i writes
        __hip_atomic_fetch_add(cnt, 1, __ATOMIC_ACQ_REL, __HIP_MEMORY_SCOPE_AGENT);
        while (__hip_atomic_load(cnt, __ATOMIC_ACQUIRE, __HIP_MEMORY_SCOPE_AGENT)
               < target)
            __builtin_amdgcn_s_sleep(1);
        __threadfence();                                  // acquire for this CU
    }
    __syncthreads();
}

// ---------------------------------------------------------------------------
// Persistent fused chain: conv1..conv4 with grid barriers between stages.
// LDS = max over stages (RECB = 34816) -> 4 blocks/CU by LDS. NO min-waves
// clamp: R7's (256,4) forced VGPR=64 and spilled; natural regalloc is the fix.
// ---------------------------------------------------------------------------
__global__ __launch_bounds__(256)
void fused_chain(const float* __restrict__ feat0, const float* __restrict__ feat1,
                 const __hip_bfloat16* __restrict__ WT1,
                 const __hip_bfloat16* __restrict__ WT2,
                 const __hip_bfloat16* __restrict__ WT3,
                 const __hip_bfloat16* __restrict__ WT4,
                 const float* __restrict__ b1, const float* __restrict__ b2,
                 const float* __restrict__ b3, const float* __restrict__ b4,
                 __hip_bfloat16* __restrict__ BUF1, __hip_bfloat16* __restrict__ BUF2,
                 float* __restrict__ avg_out, float* __restrict__ acc,
                 int* __restrict__ cnt)
{
    constexpr int LDSZ = 64*272*2;                 // 34816: max over stages
    __shared__ alignas(16) char slab[LDSZ + 32];
    __shared__ float wred[4];
    constexpr size_t B1E = (size_t)B_*PH*PW*32;    // bf16-elem modality stride
    constexpr size_t B2E = (size_t)B_*PH*PW*16;
    const int gsz = gridDim.x;

    int tx, ty, bz, mz;
    auto dec = [&](int t) {
        tx = t & 3; ty = (t >> 2) & 31; bz = (t >> 7) & 7; mz = t >> 10;
    };

    for (int t = blockIdx.x; t < 2048; t += gsz) {
        dec(t);
        conv_tile<64,32,false,true ,false>(tx,ty,bz,mz, slab, wred,
            feat0, feat1, WT1, b1, BUF1, B1E,
            nullptr, nullptr, nullptr, nullptr, nullptr);
    }
    grid_sync(cnt, 1*gsz);
    for (int t = blockIdx.x; t < 2048; t += gsz) {
        dec(t);
        conv_tile<32,16,false,false,false>(tx,ty,bz,mz, slab, wred,
            BUF1, BUF1 + B1E, WT2, b2, BUF2, B2E,
            nullptr, nullptr, nullptr, nullptr, nullptr);
    }
    grid_sync(cnt, 2*gsz);
    for (int t = blockIdx.x; t < 2048; t += gsz) {
        dec(t);
        conv_tile<16,32,false,false,false>(tx,ty,bz,mz, slab, wred,
            BUF2, BUF2 + B2E, WT3, b3, BUF1, B1E,
            nullptr, nullptr, nullptr, nullptr, nullptr);
    }
    grid_sync(cnt, 3*gsz);
    for (int t = blockIdx.x; t < 2048; t += gsz) {
        dec(t);        // (s,m0) then (s,m1): feat0 tile L2-warm for AVG
        conv_tile<32,64,true ,false,true >(tx,ty,bz,mz, slab, wred,
            BUF1, BUF1 + B1E, WT4, b4, nullptr, 0,
            feat0, feat1, feat0, avg_out, acc);
    }
}

// ---------------------------------------------------------------------------
// Standalone per-stage kernels (fallback path only).
// ---------------------------------------------------------------------------
template<int Ci, int Co, bool LOSS, bool NCHW_IN, bool AVG>
__global__ __launch_bounds__(256)
void conv_mfma(const void* __restrict__ inA, const void* __restrict__ inB,
               const __hip_bfloat16* __restrict__ wt, const float* __restrict__ bias,
               __hip_bfloat16* __restrict__ outp, size_t out_mstride,
               const float* __restrict__ ref0, const float* __restrict__ ref1,
               const float* __restrict__ other, float* __restrict__ avg_out,
               float* __restrict__ acc_out)
{
    constexpr int LDSZ = conv_cfg<Ci,Co,LOSS,NCHW_IN>::LDSZ;
    __shared__ alignas(16) char slab[LDSZ + 32];
    __shared__ float wred[4];
    conv_tile<Ci,Co,LOSS,NCHW_IN,AVG>(blockIdx.x, blockIdx.y,
        blockIdx.z & 7, blockIdx.z >> 3, slab, wred,
        inA, inB, wt, bias, outp, out_mstride, ref0, ref1, other, avg_out, acc_out);
}

// ---------------------------------------------------------------------------
// Border-zero work item: pad cells of a padded NHWC buffer (772 px / image).
// ---------------------------------------------------------------------------
template<int C>
__device__ __forceinline__ void zb_item(__hip_bfloat16* buf, int idx)
{
    constexpr int CP = C/8;
    int cb   = idx % CP;
    int cell = (idx / CP) % 772;
    int img  = idx / (CP*772);
    int row, colp;
    if (cell < 258)      { row = 0;   colp = cell; }
    else if (cell < 516) { row = 129; colp = cell - 258; }
    else { int r2 = cell - 516; row = 1 + (r2 >> 1); colp = (r2 & 1) ? 257 : 0; }
    short8 z = (short8)0;
    *(short8*)(buf + (((size_t)img*PH + row)*PW + colp)*C + cb*8) = z;
}

// ---------------------------------------------------------------------------
// OIHW fp32 -> [KC][Co][32] bf16 B-operand work item.
// ---------------------------------------------------------------------------
template<int Ci, int Co>
__device__ __forceinline__ void wt_item(const float* __restrict__ w,
                                        __hip_bfloat16* __restrict__ wt, int idx)
{
    int kl = idx & 31;
    int co = (idx >> 5) % Co;
    int kc = idx / (32*Co);
    float val = 0.f;
    if constexpr (Ci >= 32) {
        int c2 = kc / 9, t = kc % 9;
        int dy = t/3, dx = t%3;
        int ci = c2*32 + kl;
        val = w[((size_t)(co*Ci + ci)*3 + dy)*3 + dx];
    } else {
        int dy = kc >> 1, half = kc & 1;
        int dx = half*2 + (kl >> 4);
        int ci = kl & 15;
        if (dx < 3) val = w[((size_t)(co*Ci + ci)*3 + dy)*3 + dx];
    }
    wt[idx] = __float2bfloat16(val);
}

// ---------------------------------------------------------------------------
// One setup dispatch: border zeros (both modalities) + 4 wt transforms +
// acc=0 + barrier counter = 0. Total 121728 items.
// ---------------------------------------------------------------------------
__global__ __launch_bounds__(256)
void setup_kernel(const float* __restrict__ w1, const float* __restrict__ w2,
                  const float* __restrict__ w3, const float* __restrict__ w4,
                  __hip_bfloat16* WT1, __hip_bfloat16* WT2,
                  __hip_bfloat16* WT3, __hip_bfloat16* WT4,
                  __hip_bfloat16* BUF1, __hip_bfloat16* BUF2,
                  float* acc, int* cnt)
{
    int idx = blockIdx.x*256 + threadIdx.x;
    if (idx == 0) { *acc = 0.f; *cnt = 0; }
    if      (idx <  49408) zb_item<32>(BUF1, idx);
    else if (idx <  74112) zb_item<16>(BUF2, idx - 49408);
    else if (idx <  92544) wt_item<64,32>(w1, WT1, idx - 74112);
    else if (idx <  97152) wt_item<32,16>(w2, WT2, idx - 92544);
    else if (idx < 103296) wt_item<16,32>(w3, WT3, idx - 97152);
    else if (idx < 121728) wt_item<32,64>(w4, WT4, idx - 103296);
}

// fused_feat = 0.5*(feat0+feat1) exactly. Fallback path only.
__global__ __launch_bounds__(256)
void fused_avg_kernel(const float4* __restrict__ a, const float4* __restrict__ b,
                      float4* __restrict__ o, int n4)
{
    int i = blockIdx.x*256 + threadIdx.x;
    if (i < n4) {
        float4 x = a[i], y = b[i];
        float4 r;
        r.x = 0.5f*(x.x + y.x);
        r.y = 0.5f*(x.y + y.y);
        r.z = 0.5f*(x.z + y.z);
        r.w = 0.5f*(x.w + y.w);
        o[i] = r;
    }
}

extern "C" void kernel_launch(void* const* d_in, const int* in_sizes, int n_in,
                              void* d_out, int out_size, void* d_ws, size_t ws_size,
                              hipStream_t stream)
{
    const float* feat0 = (const float*)d_in[0];
    const float* feat1 = (const float*)d_in[1];
    const float* w1 = (const float*)d_in[2];
    const float* b1 = (const float*)d_in[3];
    const float* w2 = (const float*)d_in[4];
    const float* b2 = (const float*)d_in[5];
    const float* w3 = (const float*)d_in[6];
    const float* b3 = (const float*)d_in[7];
    const float* w4 = (const float*)d_in[8];
    const float* b4 = (const float*)d_in[9];

    float* out = (float*)d_out;
    float* acc = out + NPIX;                 // loss output slot

    // Scratch layout (total 51,612,736 B):
    //   BUF1[2] @ 0 (2 x 17,172,480) | BUF2[2] @ 34344960 (2 x 8,586,240)
    //   WT1 @ 51517440 | WT2 @ 51554304 | WT3 @ 51563520 | WT4 @ 51575808
    //   barrier counter @ 51612672
    constexpr size_t B1B = (size_t)B_*PH*PW*32*2;
    constexpr size_t SCR_SZ = 51612736;
    const bool use_ws = (d_ws != nullptr) && (ws_size >= SCR_SZ);
    char* sb = use_ws ? (char*)d_ws : (char*)d_out;  // fallback: out written last

    __hip_bfloat16* BUF1 = (__hip_bfloat16*)(sb + 0);
    __hip_bfloat16* BUF2 = (__hip_bfloat16*)(sb + 2*B1B);
    __hip_bfloat16* WT1  = (__hip_bfloat16*)(sb + 51517440);
    __hip_bfloat16* WT2  = (__hip_bfloat16*)(sb + 51554304);
    __hip_bfloat16* WT3  = (__hip_bfloat16*)(sb + 51563520);
    __hip_bfloat16* WT4  = (__hip_bfloat16*)(sb + 51575808);
    int*            CNT  = (int*)(sb + 51612672);

    setup_kernel<<<476, 256, 0, stream>>>(w1, w2, w3, w4,
                                          WT1, WT2, WT3, WT4, BUF1, BUF2, acc, CNT);

    // Exact co-resident grid for the persistent kernel (cached).
    static int g_nblk = 0;
    if (g_nblk == 0) {
        int bpc = 0;
        if (hipOccupancyMaxActiveBlocksPerMultiprocessor(&bpc, fused_chain, 256, 0)
                != hipSuccess || bpc < 1)
            bpc = 0;
        int dev = 0; hipGetDevice(&dev);
        int ncu = 0;
        if (hipDeviceGetAttribute(&ncu, hipDeviceAttributeMultiprocessorCount, dev)
                != hipSuccess || ncu <= 0)
            ncu = 256;
        g_nblk = (bpc >= 1) ? bpc * ncu : -1;
        if (g_nblk > 2048) g_nblk = 2048;
    }

    constexpr size_t B1E = B1B/2;
    constexpr size_t B2E = (size_t)B_*PH*PW*16;

    if (use_ws && g_nblk > 0) {
        fused_chain<<<g_nblk, 256, 0, stream>>>(
            feat0, feat1, WT1, WT2, WT3, WT4, b1, b2, b3, b4,
            BUF1, BUF2, out, acc, CNT);
    } else {
        dim3 cgrid(W_/64, H_/4, 2*B_);
        dim3 blk(256);
        conv_mfma<64,32,false,true ,false><<<cgrid, blk, 0, stream>>>(
            feat0, feat1, WT1, b1, BUF1, B1E,
            nullptr, nullptr, nullptr, nullptr, nullptr);
        conv_mfma<32,16,false,false,false><<<cgrid, blk, 0, stream>>>(
            BUF1, BUF1 + B1E, WT2, b2, BUF2, B2E,
            nullptr, nullptr, nullptr, nullptr, nullptr);
        conv_mfma<16,32,false,false,false><<<cgrid, blk, 0, stream>>>(
            BUF2, BUF2 + B2E, WT3, b3, BUF1, B1E,
            nullptr, nullptr, nullptr, nullptr, nullptr);
        if (use_ws)
            conv_mfma<32,64,true ,false,true ><<<cgrid, blk, 0, stream>>>(
                BUF1, BUF1 + B1E, WT4, b4, nullptr, 0,
                feat0, feat1, feat0, out, acc);
        else {
            conv_mfma<32,64,true ,false,false><<<cgrid, blk, 0, stream>>>(
                BUF1, BUF1 + B1E, WT4, b4, nullptr, 0,
                feat0, feat1, nullptr, nullptr, acc);
            int n4 = NPIX/4;
            fused_avg_kernel<<<(n4 + 255)/256, 256, 0, stream>>>(
                (const float4*)feat0, (const float4*)feat1, (float4*)out, n4);
        }
    }
}